// Round 6
// baseline (783.881 us; speedup 1.0000x reference)
//
#include <hip/hip_runtime.h>

#define T_STEPS 336
#define NWG 32
#define NREP 8

typedef unsigned long long u64;

// Device-global scratch. Replica slot tags are re-initialized by their OWNING
// WG at lstm startup each call (first call: .bss zeros = tag0|h0=0, exactly
// the valid t=0 state; later calls: stale tags 336/335 never match 0/1).
__device__ float g_h[337 * 512];      // h_1..h_336 (head reads t>=81)
__device__ float g_blw[256 * 512];    // sampled BayesianLinear weight
// 8 replicas x 2 parities x 8 wave-windows x 64 slots: (tag<<32)|h_bits.
// Replication divides per-line poll contention: consumer WG r polls replica
// r&7, so each 512B window is polled by 4 waves (was 32 at round-0, 8 at
// round-5 — the confirmed contention axis).
__device__ u64   g_rep[NREP][2][8][64];

__device__ __forceinline__ float softplus_f(float x) {
  return (x > 20.f) ? x : log1pf(__expf(x));
}
__device__ __forceinline__ float sigmoid_f(float x) {
  return 1.f / (1.f + __expf(-x));
}
__device__ __forceinline__ float tanh_f(float x) {
  x = fminf(fmaxf(x, -15.f), 15.f);
  float e = __expf(-2.f * x);
  return (1.f - e) / (1.f + e);
}

// ---------------- persistent LSTM recurrence ----------------
// 32 WGs x 512 threads; proven round-0/5 structure (relaxed agent publish,
// tag-polling, parity double-buffer, one barrier/step) with three levers on
// the measured per-step decomposition (1.71us = visibility + discovery
// cadence + compute tail):
//  1) NREP=8: 4 poll-waves per 512B window (round-5 confirmed contention axis).
//  2) 2-deep pipelined poll (vmcnt(1) rotation): discovery check cadence
//     RT -> RT/2. Round-4's 3-deep version melted down at 32 readers/window
//     x3 rate; at NREP=8 x2 rate the queue pressure is ~8 reader-equivalents
//     — 4x BELOW the stable round-0 point. Every-4th-rotation proven
//     __hip_atomic_load probe = correctness insurance (round-4-proven).
//  3) Post-publish s_waitcnt vmcnt(0) in the producer wave: force the publish
//     out of the CU write queue immediately; wave0's subsequent poll wait
//     absorbs the flush (free).
// Rounds 1-3 lesson: sc0 games never transport; post-barrier republish
// deadlocks. Neither is used.
// WG r owns h-indices [16r,16r+16). Thread (seg=tid>>6, cl=tid&63):
// col=(cl>>4)*512+16r+(cl&15), rows [64seg,64seg+64), 64 sampled Whh weights
// in registers (FULL unroll or w[] demotes to scratch). Wave seg polls exactly
// the 64 h-slots its dot consumes -> no poll->dot barrier; part[] parity-
// double-buffered -> single __syncthreads per step.
__global__ __launch_bounds__(512) void lstm_kernel(
    const float* __restrict__ x, const float* __restrict__ drop_x,
    const float* __restrict__ wih_mu, const float* __restrict__ wih_rho, const float* __restrict__ eps_wih,
    const float* __restrict__ b_mu, const float* __restrict__ b_rho, const float* __restrict__ eps_b,
    const float* __restrict__ whh_mu, const float* __restrict__ whh_rho, const float* __restrict__ eps_whh,
    const float* __restrict__ blw_mu, const float* __restrict__ blw_rho, const float* __restrict__ eps_blw)
{
  const int r = blockIdx.x;         // 0..31
  const int tid = threadIdx.x;      // 0..511
  const int cl = tid & 63;
  const int seg = tid >> 6;         // 0..7
  const int gate = cl >> 4, kl = cl & 15;
  const int col = gate * 512 + r * 16 + kl;
  const int row0 = seg * 64;
  const int rep = r & (NREP - 1);   // my WG's poll replica

  // FIRST: re-tag my own 16 slots for t=0 (all replicas, both parities).
  // Owners-only -> no cross-WG write races; consumers' t=0 polls wait for
  // these stores (or hit first-launch .bss zeros = valid t=0 state).
  if (tid < 16) {
    const int idx = r * 16 + tid;
    const int sw = idx >> 6, sc = idx & 63;
    #pragma unroll
    for (int q = 0; q < NREP; ++q) {
      __hip_atomic_store(&g_rep[q][0][sw][sc], 0ULL, __ATOMIC_RELAXED, __HIP_MEMORY_SCOPE_AGENT);
      __hip_atomic_store(&g_rep[q][1][sw][sc], 0ULL, __ATOMIC_RELAXED, __HIP_MEMORY_SCOPE_AGENT);
    }
  }

  __shared__ float xd[336 * 16];    // x*drop_x for batch 255
  __shared__ float hs[512];         // fp32 h copy (wave-local segments)
  __shared__ float part[2][8][64];  // parity-double-buffered partials

  // One-time: sample BLW (consumed by head after this kernel completes).
  {
    const int e0 = (r * 512 + tid) * 8;
    #pragma unroll
    for (int q = 0; q < 8; ++q) {
      const int e = e0 + q;
      g_blw[e] = blw_mu[e] + softplus_f(blw_rho[e]) * eps_blw[e];
    }
  }

  for (int e = tid; e < 5376; e += 512) {
    const int src = 255 * 5376 + e;   // batch-255 slice is contiguous
    xd[e] = x[src] * drop_x[src];
  }

  // 64 sampled Whh weights into registers.
  float w[64];
  #pragma unroll
  for (int j = 0; j < 64; ++j) {
    const int idx = (row0 + j) * 2048 + col;
    w[j] = whh_mu[idx] + softplus_f(whh_rho[idx]) * eps_whh[idx];
  }

  // Wave 0: Wih column + bias for on-the-fly xg.
  float wih[16];
  float bias = 0.f;
  if (tid < 64) {
    bias = b_mu[col] + softplus_f(b_rho[col]) * eps_b[col];
    #pragma unroll
    for (int i = 0; i < 16; ++i) {
      const int idx = i * 2048 + col;
      wih[i] = wih_mu[idx] + softplus_f(wih_rho[idx]) * eps_wih[idx];
    }
  }
  __syncthreads();                  // xd staged

  auto xg_at = [&](int t) -> float {
    const float4* xr = (const float4*)(xd + t * 16);
    float4 x0 = xr[0], x1 = xr[1], x2 = xr[2], x3 = xr[3];
    float s0 = fmaf(x0.x, wih[0], bias);
    s0 = fmaf(x0.y, wih[1], s0); s0 = fmaf(x0.z, wih[2], s0); s0 = fmaf(x0.w, wih[3], s0);
    float s1 = x1.x * wih[4];
    s1 = fmaf(x1.y, wih[5], s1); s1 = fmaf(x1.z, wih[6], s1); s1 = fmaf(x1.w, wih[7], s1);
    float s2 = x2.x * wih[8];
    s2 = fmaf(x2.y, wih[9], s2); s2 = fmaf(x2.z, wih[10], s2); s2 = fmaf(x2.w, wih[11], s2);
    float s3 = x3.x * wih[12];
    s3 = fmaf(x3.y, wih[13], s3); s3 = fmaf(x3.z, wih[14], s3); s3 = fmaf(x3.w, wih[15], s3);
    return (s0 + s1) + (s2 + s3);
  };

  float c = 0.f;                    // cell state (wave-0 lanes 0..15)
  float xgv = (tid < 64) ? xg_at(0) : 0.f;

  for (int t = 0; t < T_STEPS; ++t) {
    const int p = t & 1;

    // 2-deep pipelined poll of my replica slot. vmcnt retires in issue
    // order, so vmcnt(1) guarantees the OLDEST copy landed; check cadence =
    // RT/2 instead of RT. Every 4th rotation: proven agent probe (round-4-
    // proven insurance — degrades gracefully if sc1 loads ever mis-scope).
    u64 v0, v1, hv = 0;
    {
      const u64* slot = &g_rep[rep][p][seg][cl];
      bool done = false;
      unsigned it = 0;
      asm volatile("global_load_dwordx2 %0, %1, off sc1" : "=v"(v0) : "v"(slot) : "memory");
      asm volatile("global_load_dwordx2 %0, %1, off sc1" : "=v"(v1) : "v"(slot) : "memory");
      for (;;) {
        asm volatile("s_waitcnt vmcnt(1)" ::: "memory");
        if (!done && (unsigned)(v0 >> 32) == (unsigned)t) { hv = v0; done = true; }
        if (__all((int)done)) break;
        asm volatile("global_load_dwordx2 %0, %1, off sc1" : "=v"(v0) : "v"(slot) : "memory");
        asm volatile("s_waitcnt vmcnt(1)" ::: "memory");
        if (!done && (unsigned)(v1 >> 32) == (unsigned)t) { hv = v1; done = true; }
        if (__all((int)done)) break;
        asm volatile("global_load_dwordx2 %0, %1, off sc1" : "=v"(v1) : "v"(slot) : "memory");
        if ((++it & 3u) == 0u) {     // insurance: proven agent transport
          u64 s = __hip_atomic_load(slot, __ATOMIC_RELAXED, __HIP_MEMORY_SCOPE_AGENT);
          if (!done && (unsigned)(s >> 32) == (unsigned)t) { hv = s; done = true; }
          if (__all((int)done)) break;
        }
        if (it > (1u << 20)) break;  // anti-hang insurance (never fires: probe path proven)
      }
      hs[tid] = __uint_as_float((unsigned)hv);
    }
    // No barrier: wave seg's dot reads hs[row0..row0+64) = its own lanes' data.

    float a0 = 0.f, a1 = 0.f, a2 = 0.f, a3 = 0.f;
    const float4* hv4 = (const float4*)(hs + row0);
    #pragma unroll
    for (int jj = 0; jj < 16; ++jj) {
      float4 h4 = hv4[jj];
      a0 = fmaf(h4.x, w[4 * jj],     a0);
      a1 = fmaf(h4.y, w[4 * jj + 1], a1);
      a2 = fmaf(h4.z, w[4 * jj + 2], a2);
      a3 = fmaf(h4.w, w[4 * jj + 3], a3);
    }
    part[p][seg][cl] = (a0 + a1) + (a2 + a3);
    // Drain the residual in-flight poll (<=1) here, hidden under the dot we
    // just did; liveness pin keeps the dest pairs allocated until the drain.
    asm volatile("s_waitcnt vmcnt(0)" ::: "memory");
    asm volatile("" :: "v"(v0), "v"(v1));
    __syncthreads();   // single rendezvous per step (skew-safe via parity bufs)

    if (tid < 64) {
      float g = xgv
              + ((part[p][0][tid] + part[p][1][tid]) + (part[p][2][tid] + part[p][3][tid]))
              + ((part[p][4][tid] + part[p][5][tid]) + (part[p][6][tid] + part[p][7][tid]));
      // Parallel activation on all 64 lanes (one exp chain each):
      // gates i,f,o -> sigmoid; gate g -> tanh = 2*sigmoid(2x)-1 (clamped).
      const bool is_g = (gate == 2);
      float xin = is_g ? 2.f * fminf(fmaxf(g, -15.f), 15.f) : g;
      float s = sigmoid_f(xin);
      float act = is_g ? 2.f * s - 1.f : s;
      float vi = __shfl(act, kl);
      float vf = __shfl(act, kl + 16);
      float vg = __shfl(act, kl + 32);
      float vo = __shfl(act, kl + 48);
      if (tid < 16) {
        c = vf * c + vi * vg;
        float h = vo * tanh_f(c);
        const int idx = r * 16 + tid;
        const int sw = idx >> 6, sc = idx & 63;
        u64 pv = (((u64)(unsigned)(t + 1)) << 32) | (u64)__float_as_uint(h);
        // Publish to all replicas (distinct lines; acks drained just below).
        #pragma unroll
        for (int q = 0; q < NREP; ++q)
          __hip_atomic_store(&g_rep[q][(t + 1) & 1][sw][sc], pv,
                             __ATOMIC_RELAXED, __HIP_MEMORY_SCOPE_AGENT);
        g_h[(t + 1) * 512 + idx] = h;                  // for head (kernel-end flush)
      }
      // Force the publish out of the CU write queue NOW; wave0's next poll
      // wait (~1.4us) absorbs this flush, so it is off the critical path.
      asm volatile("s_waitcnt vmcnt(0)" ::: "memory");
      if (t + 1 < T_STEPS) xgv = xg_at(t + 1);         // off critical path
    }
  }
}

// ---------------- head ----------------
// block j: last[j] = g_h[81+j]  (reshape(T,B,H)[-1] => h_{t=80+j} of batch 255)
// y[l] = relu(last*drop_h[j] . BLW[l] + BLb[l]) * drop_l[j,l]; out = y @ lin_w^T.
// BLb sampled inline per block (256 redundant softplus -- free).
__global__ __launch_bounds__(256) void head_kernel(
    const float* __restrict__ drop_h, const float* __restrict__ drop_l,
    const float* __restrict__ blb_mu, const float* __restrict__ blb_rho,
    const float* __restrict__ eps_blb,
    const float* __restrict__ lin_w, float* __restrict__ out)
{
  const int j = blockIdx.x, tid = threadIdx.x;
  __shared__ float hd[512];
  __shared__ float y[256];

  for (int k = tid; k < 512; k += 256)
    hd[k] = g_h[(81 + j) * 512 + k] * drop_h[j * 512 + k];
  __syncthreads();

  {
    const int l = tid;
    float acc = blb_mu[l] + softplus_f(blb_rho[l]) * eps_blb[l];
    const float* wrow = g_blw + l * 512;
    #pragma unroll 8
    for (int k = 0; k < 512; ++k) acc = fmaf(hd[k], wrow[k], acc);
    acc = fmaxf(acc, 0.f);
    y[l] = acc * drop_l[j * 256 + l];
  }
  __syncthreads();

  if (tid < 10) {
    float acc = 0.f;
    const float* lrow = lin_w + tid * 256;
    #pragma unroll 8
    for (int l = 0; l < 256; ++l) acc = fmaf(y[l], lrow[l], acc);
    out[j * 10 + tid] = acc;
  }
}

// ---------------- launch (2 dispatches) ----------------
extern "C" void kernel_launch(void* const* d_in, const int* in_sizes, int n_in,
                              void* d_out, int out_size, void* d_ws, size_t ws_size,
                              hipStream_t stream) {
  const float* x        = (const float*)d_in[0];
  const float* drop_x   = (const float*)d_in[1];
  const float* drop_h   = (const float*)d_in[2];
  const float* drop_l   = (const float*)d_in[3];
  const float* wih_mu   = (const float*)d_in[4];
  const float* wih_rho  = (const float*)d_in[5];
  const float* eps_wih  = (const float*)d_in[6];
  const float* whh_mu   = (const float*)d_in[7];
  const float* whh_rho  = (const float*)d_in[8];
  const float* eps_whh  = (const float*)d_in[9];
  const float* b_mu     = (const float*)d_in[10];
  const float* b_rho    = (const float*)d_in[11];
  const float* eps_b    = (const float*)d_in[12];
  const float* blw_mu   = (const float*)d_in[13];
  const float* blw_rho  = (const float*)d_in[14];
  const float* eps_blw  = (const float*)d_in[15];
  const float* blb_mu   = (const float*)d_in[16];
  const float* blb_rho  = (const float*)d_in[17];
  const float* eps_blb  = (const float*)d_in[18];
  const float* lin_w    = (const float*)d_in[19];

  lstm_kernel<<<NWG, 512, 0, stream>>>(x, drop_x,
                                       wih_mu, wih_rho, eps_wih,
                                       b_mu, b_rho, eps_b,
                                       whh_mu, whh_rho, eps_whh,
                                       blw_mu, blw_rho, eps_blw);

  head_kernel<<<256, 256, 0, stream>>>(drop_h, drop_l,
                                       blb_mu, blb_rho, eps_blb,
                                       lin_w, (float*)d_out);
}

// Round 7
// 698.749 us; speedup vs baseline: 1.1218x; 1.1218x over previous
//
#include <hip/hip_runtime.h>

#define T_STEPS 336
#define NWG 32
#define NREP 8
// Each 512B poll window lives in its own 4224B slab (4KB + 128B): windows land
// on distinct MALL channel/bank sets instead of packing into 16KB (round-5
// layout concentrated 128 windows onto ~64 contiguous lines -> channel
// serialization hypothesis for the residual 0.7us/step queueing term).
#define WSTRIDE 528   // u64 elements per window slab (528*8 = 4224 B)

typedef unsigned long long u64;

// Device-global scratch. Window slot tags are re-initialized by their OWNING
// WG at lstm startup each call (first call: .bss zeros = tag0|h0=0, exactly
// the valid t=0 state; later calls: stale tags 336/335 never match 0/1).
__device__ float g_h[337 * 512];      // h_1..h_336 (head reads t>=81)
__device__ float g_blw[256 * 512];    // sampled BayesianLinear weight
// NREP x 2 parities x 8 wave-windows, each a 64-slot window at widx*WSTRIDE:
// slot value = (tag<<32)|h_bits. Consumer WG r polls replica r&7 -> 4 waves
// per window (round-0: 32, round-5: 8 — the confirmed contention axis).
__device__ u64   g_rep[NREP * 2 * 8 * WSTRIDE];   // ~541 KB

__device__ __forceinline__ float softplus_f(float x) {
  return (x > 20.f) ? x : log1pf(__expf(x));
}
__device__ __forceinline__ float sigmoid_f(float x) {
  return 1.f / (1.f + __expf(-x));
}
__device__ __forceinline__ float tanh_f(float x) {
  x = fminf(fmaxf(x, -15.f), 15.f);
  float e = __expf(-2.f * x);
  return (1.f - e) / (1.f + e);
}

// ---------------- persistent LSTM recurrence ----------------
// 32 WGs x 512 threads; EXACT round-5 structure (relaxed agent-atomic publish,
// plain single-outstanding atomic-load polling — the only transport with zero
// outliers; parity double-buffer; one barrier/step) with two queue-pressure
// dividers on the confirmed contention mechanism:
//  1) NREP=8: 4 poll-waves per 512B window.
//  2) 4224B window striding: windows hit distinct MALL channels/banks.
// Round-4/6 lesson (refuted twice, structural): pipelined vmcnt(N) polling
// costs ~RT per step in the pre-barrier drain — NOT used. Rounds 1-3 lesson:
// sc0 cache-bit games never transport; post-barrier republish deadlocks —
// NOT used.
// WG r owns h-indices [16r,16r+16). Thread (seg=tid>>6, cl=tid&63):
// col=(cl>>4)*512+16r+(cl&15), rows [64seg,64seg+64), 64 sampled Whh weights
// in registers (FULL unroll or w[] demotes to scratch). Wave seg polls exactly
// the 64 h-slots its dot consumes -> no poll->dot barrier; part[] parity-
// double-buffered -> single __syncthreads per step.
__global__ __launch_bounds__(512) void lstm_kernel(
    const float* __restrict__ x, const float* __restrict__ drop_x,
    const float* __restrict__ wih_mu, const float* __restrict__ wih_rho, const float* __restrict__ eps_wih,
    const float* __restrict__ b_mu, const float* __restrict__ b_rho, const float* __restrict__ eps_b,
    const float* __restrict__ whh_mu, const float* __restrict__ whh_rho, const float* __restrict__ eps_whh,
    const float* __restrict__ blw_mu, const float* __restrict__ blw_rho, const float* __restrict__ eps_blw)
{
  const int r = blockIdx.x;         // 0..31
  const int tid = threadIdx.x;      // 0..511
  const int cl = tid & 63;
  const int seg = tid >> 6;         // 0..7
  const int gate = cl >> 4, kl = cl & 15;
  const int col = gate * 512 + r * 16 + kl;
  const int row0 = seg * 64;
  const int rep = r & (NREP - 1);   // my WG's poll replica

  // FIRST: re-tag my own 16 slots for t=0 (all replicas, both parities).
  // Owners-only -> no cross-WG write races; consumers' t=0 polls wait for
  // these stores (or hit first-launch .bss zeros = valid t=0 state).
  if (tid < 16) {
    const int idx = r * 16 + tid;
    const int sw = idx >> 6, sc = idx & 63;
    #pragma unroll
    for (int q = 0; q < NREP; ++q) {
      __hip_atomic_store(&g_rep[((q * 2 + 0) * 8 + sw) * WSTRIDE + sc], 0ULL,
                         __ATOMIC_RELAXED, __HIP_MEMORY_SCOPE_AGENT);
      __hip_atomic_store(&g_rep[((q * 2 + 1) * 8 + sw) * WSTRIDE + sc], 0ULL,
                         __ATOMIC_RELAXED, __HIP_MEMORY_SCOPE_AGENT);
    }
  }

  __shared__ float xd[336 * 16];    // x*drop_x for batch 255
  __shared__ float hs[512];         // fp32 h copy (wave-local segments)
  __shared__ float part[2][8][64];  // parity-double-buffered partials

  // One-time: sample BLW (consumed by head after this kernel completes).
  {
    const int e0 = (r * 512 + tid) * 8;
    #pragma unroll
    for (int q = 0; q < 8; ++q) {
      const int e = e0 + q;
      g_blw[e] = blw_mu[e] + softplus_f(blw_rho[e]) * eps_blw[e];
    }
  }

  for (int e = tid; e < 5376; e += 512) {
    const int src = 255 * 5376 + e;   // batch-255 slice is contiguous
    xd[e] = x[src] * drop_x[src];
  }

  // 64 sampled Whh weights into registers.
  float w[64];
  #pragma unroll
  for (int j = 0; j < 64; ++j) {
    const int idx = (row0 + j) * 2048 + col;
    w[j] = whh_mu[idx] + softplus_f(whh_rho[idx]) * eps_whh[idx];
  }

  // Wave 0: Wih column + bias for on-the-fly xg.
  float wih[16];
  float bias = 0.f;
  if (tid < 64) {
    bias = b_mu[col] + softplus_f(b_rho[col]) * eps_b[col];
    #pragma unroll
    for (int i = 0; i < 16; ++i) {
      const int idx = i * 2048 + col;
      wih[i] = wih_mu[idx] + softplus_f(wih_rho[idx]) * eps_wih[idx];
    }
  }
  __syncthreads();                  // xd staged

  auto xg_at = [&](int t) -> float {
    const float4* xr = (const float4*)(xd + t * 16);
    float4 x0 = xr[0], x1 = xr[1], x2 = xr[2], x3 = xr[3];
    float s0 = fmaf(x0.x, wih[0], bias);
    s0 = fmaf(x0.y, wih[1], s0); s0 = fmaf(x0.z, wih[2], s0); s0 = fmaf(x0.w, wih[3], s0);
    float s1 = x1.x * wih[4];
    s1 = fmaf(x1.y, wih[5], s1); s1 = fmaf(x1.z, wih[6], s1); s1 = fmaf(x1.w, wih[7], s1);
    float s2 = x2.x * wih[8];
    s2 = fmaf(x2.y, wih[9], s2); s2 = fmaf(x2.z, wih[10], s2); s2 = fmaf(x2.w, wih[11], s2);
    float s3 = x3.x * wih[12];
    s3 = fmaf(x3.y, wih[13], s3); s3 = fmaf(x3.z, wih[14], s3); s3 = fmaf(x3.w, wih[15], s3);
    return (s0 + s1) + (s2 + s3);
  };

  // Precomputed poll addresses for both parities (loop-invariant).
  const u64* slot0 = &g_rep[((rep * 2 + 0) * 8 + seg) * WSTRIDE + cl];
  const u64* slot1 = &g_rep[((rep * 2 + 1) * 8 + seg) * WSTRIDE + cl];

  float c = 0.f;                    // cell state (wave-0 lanes 0..15)
  float xgv = (tid < 64) ? xg_at(0) : 0.f;

  for (int t = 0; t < T_STEPS; ++t) {
    const int p = t & 1;

    // Poll my window slot (proven transport, baseline single-outstanding
    // rate; tag t carries the h value). 4 waves per window, windows on
    // distinct MALL channel sets -> short queues.
    {
      const u64* slot = p ? slot1 : slot0;
      u64 v;
      int it = 0;
      for (;;) {
        v = __hip_atomic_load(slot, __ATOMIC_RELAXED, __HIP_MEMORY_SCOPE_AGENT);
        if ((unsigned)(v >> 32) == (unsigned)t) break;
        if (++it > (1 << 22)) break;   // anti-hang insurance (never fires in practice)
      }
      hs[tid] = __uint_as_float((unsigned)v);
    }
    // No barrier: wave seg's dot reads hs[row0..row0+64) = its own lanes' data.

    float a0 = 0.f, a1 = 0.f, a2 = 0.f, a3 = 0.f;
    const float4* hv = (const float4*)(hs + row0);
    #pragma unroll
    for (int jj = 0; jj < 16; ++jj) {
      float4 h4 = hv[jj];
      a0 = fmaf(h4.x, w[4 * jj],     a0);
      a1 = fmaf(h4.y, w[4 * jj + 1], a1);
      a2 = fmaf(h4.z, w[4 * jj + 2], a2);
      a3 = fmaf(h4.w, w[4 * jj + 3], a3);
    }
    part[p][seg][cl] = (a0 + a1) + (a2 + a3);
    __syncthreads();   // single rendezvous per step (skew-safe via parity bufs)

    if (tid < 64) {
      float g = xgv
              + ((part[p][0][tid] + part[p][1][tid]) + (part[p][2][tid] + part[p][3][tid]))
              + ((part[p][4][tid] + part[p][5][tid]) + (part[p][6][tid] + part[p][7][tid]));
      // Parallel activation on all 64 lanes (one exp chain each):
      // gates i,f,o -> sigmoid; gate g -> tanh = 2*sigmoid(2x)-1 (clamped).
      const bool is_g = (gate == 2);
      float xin = is_g ? 2.f * fminf(fmaxf(g, -15.f), 15.f) : g;
      float s = sigmoid_f(xin);
      float act = is_g ? 2.f * s - 1.f : s;
      float vi = __shfl(act, kl);
      float vf = __shfl(act, kl + 16);
      float vg = __shfl(act, kl + 32);
      float vo = __shfl(act, kl + 48);
      if (tid < 16) {
        c = vf * c + vi * vg;
        float h = vo * tanh_f(c);
        const int idx = r * 16 + tid;
        const int sw = idx >> 6, sc = idx & 63;
        const int pp = (t + 1) & 1;
        u64 pv = (((u64)(unsigned)(t + 1)) << 32) | (u64)__float_as_uint(h);
        // Publish to all replicas (distinct slabs; fire-and-forget — acks
        // retire under the next step's poll wait, proven free in round 5).
        #pragma unroll
        for (int q = 0; q < NREP; ++q)
          __hip_atomic_store(&g_rep[((q * 2 + pp) * 8 + sw) * WSTRIDE + sc], pv,
                             __ATOMIC_RELAXED, __HIP_MEMORY_SCOPE_AGENT);
        g_h[(t + 1) * 512 + idx] = h;                  // for head (kernel-end flush)
      }
      if (t + 1 < T_STEPS) xgv = xg_at(t + 1);         // off critical path
    }
  }
}

// ---------------- head ----------------
// block j: last[j] = g_h[81+j]  (reshape(T,B,H)[-1] => h_{t=80+j} of batch 255)
// y[l] = relu(last*drop_h[j] . BLW[l] + BLb[l]) * drop_l[j,l]; out = y @ lin_w^T.
// BLb sampled inline per block (256 redundant softplus -- free).
__global__ __launch_bounds__(256) void head_kernel(
    const float* __restrict__ drop_h, const float* __restrict__ drop_l,
    const float* __restrict__ blb_mu, const float* __restrict__ blb_rho,
    const float* __restrict__ eps_blb,
    const float* __restrict__ lin_w, float* __restrict__ out)
{
  const int j = blockIdx.x, tid = threadIdx.x;
  __shared__ float hd[512];
  __shared__ float y[256];

  for (int k = tid; k < 512; k += 256)
    hd[k] = g_h[(81 + j) * 512 + k] * drop_h[j * 512 + k];
  __syncthreads();

  {
    const int l = tid;
    float acc = blb_mu[l] + softplus_f(blb_rho[l]) * eps_blb[l];
    const float* wrow = g_blw + l * 512;
    #pragma unroll 8
    for (int k = 0; k < 512; ++k) acc = fmaf(hd[k], wrow[k], acc);
    acc = fmaxf(acc, 0.f);
    y[l] = acc * drop_l[j * 256 + l];
  }
  __syncthreads();

  if (tid < 10) {
    float acc = 0.f;
    const float* lrow = lin_w + tid * 256;
    #pragma unroll 8
    for (int l = 0; l < 256; ++l) acc = fmaf(y[l], lrow[l], acc);
    out[j * 10 + tid] = acc;
  }
}

// ---------------- launch (2 dispatches) ----------------
extern "C" void kernel_launch(void* const* d_in, const int* in_sizes, int n_in,
                              void* d_out, int out_size, void* d_ws, size_t ws_size,
                              hipStream_t stream) {
  const float* x        = (const float*)d_in[0];
  const float* drop_x   = (const float*)d_in[1];
  const float* drop_h   = (const float*)d_in[2];
  const float* drop_l   = (const float*)d_in[3];
  const float* wih_mu   = (const float*)d_in[4];
  const float* wih_rho  = (const float*)d_in[5];
  const float* eps_wih  = (const float*)d_in[6];
  const float* whh_mu   = (const float*)d_in[7];
  const float* whh_rho  = (const float*)d_in[8];
  const float* eps_whh  = (const float*)d_in[9];
  const float* b_mu     = (const float*)d_in[10];
  const float* b_rho    = (const float*)d_in[11];
  const float* eps_b    = (const float*)d_in[12];
  const float* blw_mu   = (const float*)d_in[13];
  const float* blw_rho  = (const float*)d_in[14];
  const float* eps_blw  = (const float*)d_in[15];
  const float* blb_mu   = (const float*)d_in[16];
  const float* blb_rho  = (const float*)d_in[17];
  const float* eps_blb  = (const float*)d_in[18];
  const float* lin_w    = (const float*)d_in[19];

  lstm_kernel<<<NWG, 512, 0, stream>>>(x, drop_x,
                                       wih_mu, wih_rho, eps_wih,
                                       b_mu, b_rho, eps_b,
                                       whh_mu, whh_rho, eps_whh,
                                       blw_mu, blw_rho, eps_blw);

  head_kernel<<<256, 256, 0, stream>>>(drop_h, drop_l,
                                       blb_mu, blb_rho, eps_blb,
                                       lin_w, (float*)d_out);
}

// Round 8
// 689.065 us; speedup vs baseline: 1.1376x; 1.0141x over previous
//
#include <hip/hip_runtime.h>

#define T_STEPS 336
#define NWG 32
#define NREP 4

typedef unsigned long long u64;

// Device-global scratch. Replica slot tags are re-initialized by their OWNING
// WG at lstm startup each call (first call: .bss zeros = tag0|h0=0, exactly
// the valid t=0 state; later calls: stale tags 336/335 never match 0/1).
__device__ float g_h[337 * 512];      // h_1..h_336 (head reads t>=81)
__device__ float g_blwT[512 * 256];   // sampled BayesianLinear weight, TRANSPOSED [k][l]
// 4 replicas x 2 parities x 8 wave-windows x 64 slots: (tag<<32)|h_bits.
// Replication divides per-line poll contention by 4: consumer WG r polls
// replica r&3, so each 512B window is polled by 8 waves instead of 32.
// (Round-7 null: NREP=8 + channel striding gained nothing over this — the
// contention axis is exhausted at NREP=4; remaining cost is base MALL RT.)
__device__ u64   g_rep[NREP][2][8][64];

__device__ __forceinline__ float softplus_f(float x) {
  return (x > 20.f) ? x : log1pf(__expf(x));
}
__device__ __forceinline__ float sigmoid_f(float x) {
  return 1.f / (1.f + __expf(-x));
}
__device__ __forceinline__ float tanh_f(float x) {
  x = fminf(fmaxf(x, -15.f), 15.f);
  float e = __expf(-2.f * x);
  return (1.f - e) / (1.f + e);
}

// ---------------- persistent LSTM recurrence ----------------
// EXACT round-5 structure (best proven: 574us, zero outliers): 32 WGs x 512
// threads, relaxed agent-atomic publish to 4 replicas, plain single-
// outstanding atomic-load polling, parity double-buffer, one barrier/step.
// Transport ledger from rounds 1-7: sc0/sc1 cache-bit games never transport
// (r1-3); post-barrier republish deadlocks (r1); pipelined vmcnt(N) polling
// costs ~RT/step in the pre-barrier drain (r4, r6 — refuted twice); NREP=4
// replication is the one confirmed win (r5, -45us); NREP=8/striding null
// (r7). The ~1.7us/step that remains is base MALL visibility + discovery —
// structural for cross-CU spin transport.
// ONLY change vs round 5: BLW is sampled TRANSPOSED (WT[k][l]) so the head's
// inner loop is coalesced (lanes l consecutive at fixed k). Param reads stay
// contiguous; the scattered one-time WT stores are fire-and-forget.
// WG r owns h-indices [16r,16r+16). Thread (seg=tid>>6, cl=tid&63):
// col=(cl>>4)*512+16r+(cl&15), rows [64seg,64seg+64), 64 sampled Whh weights
// in registers (FULL unroll or w[] demotes to scratch). Wave seg polls exactly
// the 64 h-slots its dot consumes -> no poll->dot barrier; part[] parity-
// double-buffered -> single __syncthreads per step.
__global__ __launch_bounds__(512) void lstm_kernel(
    const float* __restrict__ x, const float* __restrict__ drop_x,
    const float* __restrict__ wih_mu, const float* __restrict__ wih_rho, const float* __restrict__ eps_wih,
    const float* __restrict__ b_mu, const float* __restrict__ b_rho, const float* __restrict__ eps_b,
    const float* __restrict__ whh_mu, const float* __restrict__ whh_rho, const float* __restrict__ eps_whh,
    const float* __restrict__ blw_mu, const float* __restrict__ blw_rho, const float* __restrict__ eps_blw)
{
  const int r = blockIdx.x;         // 0..31
  const int tid = threadIdx.x;      // 0..511
  const int cl = tid & 63;
  const int seg = tid >> 6;         // 0..7
  const int gate = cl >> 4, kl = cl & 15;
  const int col = gate * 512 + r * 16 + kl;
  const int row0 = seg * 64;
  const int rep = r & (NREP - 1);   // my WG's poll replica

  // FIRST: re-tag my own 16 slots for t=0 (all replicas, both parities).
  // Owners-only -> no cross-WG write races; consumers' t=0 polls wait for
  // these stores (or hit first-launch .bss zeros = valid t=0 state).
  if (tid < 16) {
    const int idx = r * 16 + tid;
    const int sw = idx >> 6, sc = idx & 63;
    #pragma unroll
    for (int q = 0; q < NREP; ++q) {
      __hip_atomic_store(&g_rep[q][0][sw][sc], 0ULL, __ATOMIC_RELAXED, __HIP_MEMORY_SCOPE_AGENT);
      __hip_atomic_store(&g_rep[q][1][sw][sc], 0ULL, __ATOMIC_RELAXED, __HIP_MEMORY_SCOPE_AGENT);
    }
  }

  __shared__ float xd[336 * 16];    // x*drop_x for batch 255
  __shared__ float hs[512];         // fp32 h copy (wave-local segments)
  __shared__ float part[2][8][64];  // parity-double-buffered partials

  // One-time: sample BLW, stored TRANSPOSED for the head's coalesced read.
  // Reads contiguous (e = l*512+k, consecutive); writes scatter (stride-1KB),
  // fire-and-forget, hidden under startup.
  {
    const int e0 = (r * 512 + tid) * 8;
    #pragma unroll
    for (int q = 0; q < 8; ++q) {
      const int e = e0 + q;                 // e = l*512 + k
      const float wv = blw_mu[e] + softplus_f(blw_rho[e]) * eps_blw[e];
      g_blwT[(e & 511) * 256 + (e >> 9)] = wv;   // WT[k][l]
    }
  }

  for (int e = tid; e < 5376; e += 512) {
    const int src = 255 * 5376 + e;   // batch-255 slice is contiguous
    xd[e] = x[src] * drop_x[src];
  }

  // 64 sampled Whh weights into registers.
  float w[64];
  #pragma unroll
  for (int j = 0; j < 64; ++j) {
    const int idx = (row0 + j) * 2048 + col;
    w[j] = whh_mu[idx] + softplus_f(whh_rho[idx]) * eps_whh[idx];
  }

  // Wave 0: Wih column + bias for on-the-fly xg.
  float wih[16];
  float bias = 0.f;
  if (tid < 64) {
    bias = b_mu[col] + softplus_f(b_rho[col]) * eps_b[col];
    #pragma unroll
    for (int i = 0; i < 16; ++i) {
      const int idx = i * 2048 + col;
      wih[i] = wih_mu[idx] + softplus_f(wih_rho[idx]) * eps_wih[idx];
    }
  }
  __syncthreads();                  // xd staged

  auto xg_at = [&](int t) -> float {
    const float4* xr = (const float4*)(xd + t * 16);
    float4 x0 = xr[0], x1 = xr[1], x2 = xr[2], x3 = xr[3];
    float s0 = fmaf(x0.x, wih[0], bias);
    s0 = fmaf(x0.y, wih[1], s0); s0 = fmaf(x0.z, wih[2], s0); s0 = fmaf(x0.w, wih[3], s0);
    float s1 = x1.x * wih[4];
    s1 = fmaf(x1.y, wih[5], s1); s1 = fmaf(x1.z, wih[6], s1); s1 = fmaf(x1.w, wih[7], s1);
    float s2 = x2.x * wih[8];
    s2 = fmaf(x2.y, wih[9], s2); s2 = fmaf(x2.z, wih[10], s2); s2 = fmaf(x2.w, wih[11], s2);
    float s3 = x3.x * wih[12];
    s3 = fmaf(x3.y, wih[13], s3); s3 = fmaf(x3.z, wih[14], s3); s3 = fmaf(x3.w, wih[15], s3);
    return (s0 + s1) + (s2 + s3);
  };

  float c = 0.f;                    // cell state (wave-0 lanes 0..15)
  float xgv = (tid < 64) ? xg_at(0) : 0.f;

  for (int t = 0; t < T_STEPS; ++t) {
    const int p = t & 1;

    // Poll my replica slot (proven transport, baseline rate; tag t carries
    // the h value). Only 8 waves poll this 512B window -> short MALL queues.
    {
      const u64* slot = &g_rep[rep][p][seg][cl];
      u64 v;
      int it = 0;
      for (;;) {
        v = __hip_atomic_load(slot, __ATOMIC_RELAXED, __HIP_MEMORY_SCOPE_AGENT);
        if ((unsigned)(v >> 32) == (unsigned)t) break;
        if (++it > (1 << 22)) break;   // anti-hang insurance (never fires in practice)
      }
      hs[tid] = __uint_as_float((unsigned)v);
    }
    // No barrier: wave seg's dot reads hs[row0..row0+64) = its own lanes' data.

    float a0 = 0.f, a1 = 0.f, a2 = 0.f, a3 = 0.f;
    const float4* hv = (const float4*)(hs + row0);
    #pragma unroll
    for (int jj = 0; jj < 16; ++jj) {
      float4 h4 = hv[jj];
      a0 = fmaf(h4.x, w[4 * jj],     a0);
      a1 = fmaf(h4.y, w[4 * jj + 1], a1);
      a2 = fmaf(h4.z, w[4 * jj + 2], a2);
      a3 = fmaf(h4.w, w[4 * jj + 3], a3);
    }
    part[p][seg][cl] = (a0 + a1) + (a2 + a3);
    __syncthreads();   // single rendezvous per step (skew-safe via parity bufs)

    if (tid < 64) {
      float g = xgv
              + ((part[p][0][tid] + part[p][1][tid]) + (part[p][2][tid] + part[p][3][tid]))
              + ((part[p][4][tid] + part[p][5][tid]) + (part[p][6][tid] + part[p][7][tid]));
      // Parallel activation on all 64 lanes (one exp chain each):
      // gates i,f,o -> sigmoid; gate g -> tanh = 2*sigmoid(2x)-1 (clamped).
      const bool is_g = (gate == 2);
      float xin = is_g ? 2.f * fminf(fmaxf(g, -15.f), 15.f) : g;
      float s = sigmoid_f(xin);
      float act = is_g ? 2.f * s - 1.f : s;
      float vi = __shfl(act, kl);
      float vf = __shfl(act, kl + 16);
      float vg = __shfl(act, kl + 32);
      float vo = __shfl(act, kl + 48);
      if (tid < 16) {
        c = vf * c + vi * vg;
        float h = vo * tanh_f(c);
        const int idx = r * 16 + tid;
        const int sw = idx >> 6, sc = idx & 63;
        u64 pv = (((u64)(unsigned)(t + 1)) << 32) | (u64)__float_as_uint(h);
        // Publish to all 4 replicas (fire-and-forget; acks retire under the
        // next step's poll wait, same as the baseline's single store).
        #pragma unroll
        for (int q = 0; q < NREP; ++q)
          __hip_atomic_store(&g_rep[q][(t + 1) & 1][sw][sc], pv,
                             __ATOMIC_RELAXED, __HIP_MEMORY_SCOPE_AGENT);
        g_h[(t + 1) * 512 + idx] = h;                  // for head (kernel-end flush)
      }
      if (t + 1 < T_STEPS) xgv = xg_at(t + 1);         // off critical path
    }
  }
}

// ---------------- head ----------------
// block j: last[j] = g_h[81+j]  (reshape(T,B,H)[-1] => h_{t=80+j} of batch 255)
// y[l] = relu(last*drop_h[j] . BLW[l] + BLb[l]) * drop_l[j,l]; out = y @ lin_w^T.
// BLW is stored transposed (WT[k][l]) by the lstm kernel, so the inner loop
// is COALESCED: at fixed k, lanes l read consecutive addresses (one 1KB
// wave-line stream instead of a 64-line gather per instruction — the round-7
// head burned ~most of the constant 113us total-lstm gap on that gather).
// BLb sampled inline per block (256 redundant softplus -- free).
__global__ __launch_bounds__(256) void head_kernel(
    const float* __restrict__ drop_h, const float* __restrict__ drop_l,
    const float* __restrict__ blb_mu, const float* __restrict__ blb_rho,
    const float* __restrict__ eps_blb,
    const float* __restrict__ lin_w, float* __restrict__ out)
{
  const int j = blockIdx.x, tid = threadIdx.x;
  __shared__ float hd[512];
  __shared__ float y[256];

  for (int k = tid; k < 512; k += 256)
    hd[k] = g_h[(81 + j) * 512 + k] * drop_h[j * 512 + k];
  __syncthreads();

  {
    const int l = tid;
    float acc = blb_mu[l] + softplus_f(blb_rho[l]) * eps_blb[l];
    #pragma unroll 8
    for (int k = 0; k < 512; ++k)
      acc = fmaf(hd[k], g_blwT[k * 256 + l], acc);   // coalesced across lanes
    acc = fmaxf(acc, 0.f);
    y[l] = acc * drop_l[j * 256 + l];
  }
  __syncthreads();

  if (tid < 10) {
    float acc = 0.f;
    const float* lrow = lin_w + tid * 256;
    #pragma unroll 8
    for (int l = 0; l < 256; ++l) acc = fmaf(y[l], lrow[l], acc);
    out[j * 10 + tid] = acc;
  }
}

// ---------------- launch (2 dispatches) ----------------
extern "C" void kernel_launch(void* const* d_in, const int* in_sizes, int n_in,
                              void* d_out, int out_size, void* d_ws, size_t ws_size,
                              hipStream_t stream) {
  const float* x        = (const float*)d_in[0];
  const float* drop_x   = (const float*)d_in[1];
  const float* drop_h   = (const float*)d_in[2];
  const float* drop_l   = (const float*)d_in[3];
  const float* wih_mu   = (const float*)d_in[4];
  const float* wih_rho  = (const float*)d_in[5];
  const float* eps_wih  = (const float*)d_in[6];
  const float* whh_mu   = (const float*)d_in[7];
  const float* whh_rho  = (const float*)d_in[8];
  const float* eps_whh  = (const float*)d_in[9];
  const float* b_mu     = (const float*)d_in[10];
  const float* b_rho    = (const float*)d_in[11];
  const float* eps_b    = (const float*)d_in[12];
  const float* blw_mu   = (const float*)d_in[13];
  const float* blw_rho  = (const float*)d_in[14];
  const float* eps_blw  = (const float*)d_in[15];
  const float* blb_mu   = (const float*)d_in[16];
  const float* blb_rho  = (const float*)d_in[17];
  const float* eps_blb  = (const float*)d_in[18];
  const float* lin_w    = (const float*)d_in[19];

  lstm_kernel<<<NWG, 512, 0, stream>>>(x, drop_x,
                                       wih_mu, wih_rho, eps_wih,
                                       b_mu, b_rho, eps_b,
                                       whh_mu, whh_rho, eps_whh,
                                       blw_mu, blw_rho, eps_blw);

  head_kernel<<<256, 256, 0, stream>>>(drop_h, drop_l,
                                       blb_mu, blb_rho, eps_blb,
                                       lin_w, (float*)d_out);
}